// Round 10
// baseline (122.489 us; speedup 1.0000x reference)
//
#include <hip/hip_runtime.h>
#include <math.h>

#define NLAT 512
#define NLON 1024
#define LMAX 50
#define MMAX 50
#define NPTS 2048
#define NIMG 4                     // (branch<<1)|b : pred b0, pred b1, targ b0, targ b1
#define M_GRID (NLAT * NLON)       // 524288

#define NBT 32                     // theta bins over [0, pi]
#define NBP 64                     // phi bins over [-pi, pi]
#define NBINS (NBT * NBP)          // 2048
#define NPAIR (2 * LMAX * MMAX)    // 5000 (b,l,m) loss terms

// exact fp32 images of numpy float32 constants
#define PI_F     3.14159274101257324e0f   // (float)pi  0x40490FDB
#define TWO_PI_F 6.28318548202514648e0f   // (float)2pi 0x40C90FDB
#define WB       (PI_F / 32.0f)           // bin width (same in both axes)
#define INV_WB   (32.0f / PI_F)

// ---------------- merged setup (blocks 0..127) + per-image binning (blocks 128..131)
__global__ __launch_bounds__(256) void k_setup_bin(const float* __restrict__ pred,
                                                   const float* __restrict__ targ,
                                                   float* __restrict__ wq,
                                                   double* __restrict__ costab,
                                                   float* __restrict__ plm,
                                                   float4* __restrict__ spts_g,
                                                   unsigned short* __restrict__ bstart_g,
                                                   double* __restrict__ acc,
                                                   int* __restrict__ counter) {
    if (blockIdx.x < 128) {
        int tid = blockIdx.x * 256 + threadIdx.x;   // 0..32767
        if (tid == 0) { acc[0] = 0.0; counter[0] = 0; }

        // --- CC weights: one wave (64 lanes) per weight j
        {
            int j = blockIdx.x * 4 + (threadIdx.x >> 6);   // 0..511
            int lane = threadIdx.x & 63;
            double t = M_PI * (double)j / 511.0;
            double S = 0.0;
            for (int k = lane + 1; k <= 255; k += 64) {
                S += cos(2.0 * t * (double)k) * (2.0 / (4.0 * (double)k * k - 1.0));
            }
            for (int off = 32; off > 0; off >>= 1) S += __shfl_down(S, off);
            if (lane == 0) {
                double c = (j == 0 || j == 511) ? 1.0 : 2.0;
                wq[j] = (float)((c / 511.0) * (1.0 - S));
            }
        }
        if (tid < 1024) {
            costab[tid] = cos(2.0 * M_PI * (double)tid / 1024.0);
        }
        if (tid < MMAX * 512) {
            int m = tid >> 9;
            int k = tid & 511;
            double theta = M_PI * (double)k / 511.0;
            double ct = cos(theta), st = sin(theta);
            double pmm = sqrt(1.0 / (4.0 * M_PI));
            for (int i = 1; i <= m; ++i) {
                pmm = -sqrt((2.0 * i + 1.0) / (2.0 * i)) * st * pmm;
            }
            plm[((size_t)m * MMAX + m) * 512 + k] = (float)pmm;
            if (m + 1 < LMAX) {
                double pm1 = sqrt(2.0 * m + 3.0) * ct * pmm;
                plm[((size_t)(m + 1) * MMAX + m) * 512 + k] = (float)pm1;
                double pm2 = pmm;
                for (int l = m + 2; l < LMAX; ++l) {
                    double ll = (double)l, mm = (double)m, lm1 = (double)(l - 1);
                    double a  = sqrt((4.0 * ll * ll - 1.0) / (ll * ll - mm * mm));
                    double bb = sqrt((lm1 * lm1 - mm * mm) / (4.0 * lm1 * lm1 - 1.0));
                    double p = a * (ct * pm1 - bb * pm2);
                    plm[((size_t)l * MMAX + m) * 512 + k] = (float)p;
                    pm2 = pm1; pm1 = p;
                }
            }
        }
        return;
    }

    // ---- binning path: one block per image
    int img = blockIdx.x - 128;
    int branch = img >> 1, b = img & 1;
    const float* src = (branch ? targ : pred) + (size_t)b * NPTS * 3;
    __shared__ float sth[NPTS], sphi[NPTS], srr[NPTS];   // 24 KB
    __shared__ int cnt[NBINS];                            // 8 KB
    __shared__ int bstart[NBINS];                         // 8 KB
    __shared__ int partial[256];
    __shared__ int binid[NPTS];                           // 8 KB
    int tid = threadIdx.x;

    for (int i = tid; i < NBINS; i += 256) cnt[i] = 0;
    for (int i = tid; i < NPTS; i += 256) {
        float x = src[3 * i], y = src[3 * i + 1], z = src[3 * i + 2];
        float r = sqrtf(x * x + y * y + z * z);
        float nyz = sqrtf(y * y + z * z);
        float phi1 = acosf(x / r);
        float base = acosf(y / nyz);
        float phi2 = (z < 0.0f) ? (TWO_PI_F - base) : base;
        sth[i] = phi1; sphi[i] = phi2 - PI_F; srr[i] = r;
    }
    __syncthreads();
    for (int i = tid; i < NPTS; i += 256) {
        int bt = min(max((int)(sth[i] * INV_WB), 0), NBT - 1);
        int bp = min(max((int)((sphi[i] + PI_F) * INV_WB), 0), NBP - 1);
        int bn = bt * NBP + bp;
        binid[i] = bn;
        atomicAdd(&cnt[bn], 1);
    }
    __syncthreads();
    // exclusive scan over 2048 bins: 8 bins per thread + scan of 256 partials
    int base = tid * 8, s = 0;
    #pragma unroll
    for (int j = 0; j < 8; ++j) s += cnt[base + j];
    partial[tid] = s;
    __syncthreads();
    for (int offs = 1; offs < 256; offs <<= 1) {
        int v = (tid >= offs) ? partial[tid - offs] : 0;
        __syncthreads();
        partial[tid] += v;
        __syncthreads();
    }
    int run = (tid == 0) ? 0 : partial[tid - 1];
    #pragma unroll
    for (int j = 0; j < 8; ++j) { bstart[base + j] = run; run += cnt[base + j]; }
    __syncthreads();
    unsigned short* bsg = bstart_g + (size_t)img * (NBINS + 1);
    for (int i = tid; i < NBINS; i += 256) {
        bsg[i] = (unsigned short)bstart[i];
        cnt[i] = bstart[i];
    }
    if (tid == 0) bsg[NBINS] = (unsigned short)NPTS;
    __syncthreads();
    float4* sg = spts_g + (size_t)img * NPTS;
    for (int i = tid; i < NPTS; i += 256) {
        int bn = binid[i];
        int pos = atomicAdd(&cnt[bn], 1);   // within-bin order nondeterministic; value-safe
        sg[pos] = make_float4(sth[i], sphi[i], srr[i], 0.0f);
    }
}

// ---------------- binned 3-NN + interp: one WAVE per 8x16 patch (2 queries/lane),
// ring scan with per-lane parallel span-bound prefetch + shfl broadcast
__global__ __launch_bounds__(512, 8) void k_nn(const float4* __restrict__ spts_g,
                                               const unsigned short* __restrict__ bstart_g,
                                               float* __restrict__ interp) {
    __shared__ float4 spts[NPTS];                  // 32 KB
    __shared__ unsigned short sstart[NBT * 65 + 1];// padded stride 65 (bank spread), 4.1 KB
    int bid = blockIdx.x;
    int img = bid >> 9;                            // 512 blocks per image
    int blk = bid & 511;
    const float4* sg = spts_g + (size_t)img * NPTS;
    const unsigned short* bsg = bstart_g + (size_t)img * (NBINS + 1);
    int tid = threadIdx.x;
    for (int i = tid; i < NPTS; i += 512) spts[i] = sg[i];
    for (int i = tid; i < NBT * 65; i += 512) {    // sstart[t*65+p] = bsg[t*64+p], p<=64
        int t = i / 65, p = i - t * 65;            // (t*64+64 == start of row t+1; t=31,p=64 -> 2048)
        sstart[i] = bsg[t * 64 + p];
    }
    __syncthreads();

    // 8 waves/block; wave w -> patch blk*8+w of a 64x64 grid of 8(theta)x16(phi) patches
    int w = tid >> 6, lane = tid & 63;
    int patch = blk * 8 + w;
    int pi = patch >> 6, pj = patch & 63;
    int qi = lane >> 3, qj0 = (lane & 7) * 2;      // two phi-adjacent queries per lane
    int gi = pi * 8 + qi;
    int gj0 = pj * 16 + qj0, gj1 = gj0 + 1;
    float gt  = (float)gi * (1.0f / 512.0f) * PI_F;
    float gp0 = (float)(gj0 - 512) * (1.0f / 512.0f) * PI_F;   // independent rounding:
    float gp1 = (float)(gj1 - 512) * (1.0f / 512.0f) * PI_F;   // exact fp32 ref match
    int qbt  = min(max((int)(gt * INV_WB), 0), NBT - 1);
    int qbp0 = min(max((int)((gp0 + PI_F) * INV_WB), 0), NBP - 1);
    int qbp1 = min(max((int)((gp1 + PI_F) * INV_WB), 0), NBP - 1);
    // binning monotone in gi/gj -> lane 0 query0 is bbox min, lane 63 query1 is bbox max
    int bt0 = __shfl(qbt, 0), bt1 = __shfl(qbt, 63);
    int bp0 = __shfl(qbp0, 0), bp1 = __shfl(qbp1, 63);

    float da0 = 1e30f, da1 = 1e30f, da2 = 1e30f;   // top-3 for query A (gp0)
    float ra0 = 0.0f, ra1 = 0.0f, ra2 = 0.0f;
    float db0 = 1e30f, db1 = 1e30f, db2 = 1e30f;   // top-3 for query B (gp1)
    float rb0 = 0.0f, rb1 = 0.0f, rb2 = 0.0f;

    auto scan_range = [&](int s, int e) {
        for (int i = s; i < e; ++i) {
            float4 pt = spts[i];                   // wave-uniform LDS read: broadcast
            float dx  = gt - pt.x;
            float dxx = dx * dx;
            float dy0 = gp0 - pt.y;
            float dy1 = gp1 - pt.y;
            float dA  = fmaf(dy0, dy0, dxx);
            float dB  = fmaf(dy1, dy1, dxx);
            if (__any(dA < da2 || dB < db2)) {     // wave-uniform skip of the inserts
                float rv = pt.z;
                bool c2 = dA < da2, c1 = dA < da1, c0 = dA < da0;
                da2 = c1 ? da1 : (c2 ? dA : da2);   ra2 = c1 ? ra1 : (c2 ? rv : ra2);
                da1 = c0 ? da0 : (c1 ? dA : da1);   ra1 = c0 ? ra0 : (c1 ? rv : ra1);
                da0 = c0 ? dA : da0;                ra0 = c0 ? rv : ra0;
                bool e2 = dB < db2, e1 = dB < db1, e0 = dB < db0;
                db2 = e1 ? db1 : (e2 ? dB : db2);   rb2 = e1 ? rb1 : (e2 ? rv : rb2);
                db1 = e0 ? db0 : (e1 ? dB : db1);   rb1 = e0 ? rb0 : (e1 ? rv : rb1);
                db0 = e0 ? dB : db0;                rb0 = e0 ? rv : rb0;
            }
        }
    };

    // r = 0: bbox rows bt0..bt1 span [bp0..bp1] -- parallel bound fetch, shfl broadcast
    {
        int nsp = bt1 - bt0 + 1;                   // <= 3
        int se = 0;
        if (lane < nsp) {
            int t = bt0 + lane;
            int s = sstart[t * 65 + bp0];
            int e = sstart[t * 65 + bp1 + 1];
            se = s | (e << 16);
        }
        for (int k = 0; k < nsp; ++k) {
            int sek = __shfl(se, k);
            scan_range(sek & 0xffff, sek >> 16);
        }
    }
    for (int r = 1; r <= 70; ++r) {
        if (r >= 2) {
            // rings 0..r-1 complete: unscanned points are >= (r-1)*WB away
            // (d2 = 1e30 until 3 inserts -> bound test fails automatically)
            float bnd = (float)(r - 1) * WB * 0.999f;
            float b2 = bnd * bnd;
            if (__all(b2 > da2 && b2 > db2)) break;   // wave-level vote, no barrier
        }
        int tlo = bt0 - r, thi = bt1 + r, plo = bp0 - r, phi = bp1 + r;
        bool hasT = (tlo >= 0), hasB = (thi <= NBT - 1);
        bool hasL = (plo >= 0), hasR = (phi <= NBP - 1);
        int cplo = max(plo, 0), cphi = min(phi, NBP - 1);
        int ctlo = max(tlo + 1, 0), cthi = min(thi - 1, NBT - 1);
        int ncol = max(cthi - ctlo + 1, 0);
        int nTop = hasT ? 1 : 0, nBot = hasB ? 1 : 0;
        int nL = hasL ? ncol : 0, nR = hasR ? ncol : 0;
        int nsp = nTop + nBot + nL + nR;
        // span order identical to per-bin version: top row, bottom row, left col
        // (t ascending), right col (t ascending) -> bitwise-identical inserts
        for (int base = 0; base < nsp; base += 64) {
            int si = base + lane;
            int se = 0;
            if (si < nsp) {
                int t, p0, p1;
                int k2 = si;
                if (k2 < nTop) { t = tlo; p0 = cplo; p1 = cphi; }
                else {
                    k2 -= nTop;
                    if (k2 < nBot) { t = thi; p0 = cplo; p1 = cphi; }
                    else {
                        k2 -= nBot;
                        if (k2 < nL) { t = ctlo + k2; p0 = plo; p1 = plo; }
                        else { k2 -= nL; t = ctlo + k2; p0 = phi; p1 = phi; }
                    }
                }
                int s = sstart[t * 65 + p0];
                int e = sstart[t * 65 + p1 + 1];
                se = s | (e << 16);
            }
            int cntb = min(nsp - base, 64);
            for (int k = 0; k < cntb; ++k) {
                int sek = __shfl(se, k);
                scan_range(sek & 0xffff, sek >> 16);
            }
        }
        if (tlo <= 0 && thi >= NBT - 1 && plo <= 0 && phi >= NBP - 1) break;
    }
    float sA = da0 + da1 + da2;     // faithful: weights proportional to distance
    float sB = db0 + db1 + db2;
    float2 outv;
    outv.x = (da0 * ra0 + da1 * ra1 + da2 * ra2) / sA;
    outv.y = (db0 * rb0 + db1 * rb1 + db2 * rb2) / sB;
    *(float2*)&interp[(size_t)img * M_GRID + (size_t)gi * NLON + gj0] = outv;
}

// ---------------- DFT of the DIFFERENCE field (SHT is linear): E[b,m,k] =
// wq[k]*(2pi/N)*Re rfft(interp[pred,b]-interp[targ,b])[k,m].  1024 rows, 8 waves/blk.
__global__ __launch_bounds__(512) void k_dft(const float* __restrict__ interp,
                                             const double* __restrict__ costab,
                                             const float* __restrict__ wq,
                                             double* __restrict__ ediff) {
    __shared__ double sdf[NLON];     // 8 KB: fp64 diff of the two fp32 rows
    __shared__ double sct[NLON];     // 8 KB
    __shared__ double g[576];        // 4.5 KB (g[513..575] = 0 pad)
    int bid = blockIdx.x;            // one block per (batch, k) row: 1024 rows
    int b = bid >> 9, k = bid & 511;
    const float* rowp = interp + (size_t)b * M_GRID + (size_t)k * NLON;        // pred
    const float* rowt = interp + (size_t)(2 + b) * M_GRID + (size_t)k * NLON;  // targ
    int tid = threadIdx.x;
    for (int i = tid; i < NLON; i += 512) {
        sdf[i] = (double)rowp[i] - (double)rowt[i];   // exact in fp64
        sct[i] = costab[i];
    }
    __syncthreads();
    // fold: g[n] = d[n] + d[1024-n] (n=1..511), g[0]=d[0], g[512]=d[512]
    for (int n = tid; n < 576; n += 512) {
        double v = 0.0;
        if (n == 0) v = sdf[0];
        else if (n < 512) v = sdf[n] + sdf[1024 - n];
        else if (n == 512) v = sdf[512];
        g[n] = v;
    }
    __syncthreads();
    double scale = (double)wq[k] * (6.283185307179586 / 1024.0);
    int w = tid >> 6, lane = tid & 63;
    for (int m = w; m < MMAX; m += 8) {
        // cos/sin at theta = 2*pi*m*lane/1024; sin(x) = cos(x - pi/2) -> idx +768
        double c  = sct[(m * lane) & 1023];
        double s  = sct[(m * lane + 768) & 1023];
        double cd = sct[(m * 64) & 1023];          // rotation by delta = 2*pi*m*64/1024
        double sd = sct[(m * 64 + 768) & 1023];
        double a = 0.0;
        #pragma unroll
        for (int i = 0; i < 9; ++i) {
            int n = lane + (i << 6);               // lane-consecutive: conflict-free
            a = fma(g[n], c, a);
            double cn = fma(cd, c, -(sd * s));
            double sn = fma(cd, s, sd * c);
            c = cn; s = sn;
        }
        #pragma unroll
        for (int off = 32; off > 0; off >>= 1) a += __shfl_xor(a, off);
        if (lane == 0) {
            ediff[((size_t)b * MMAX + m) * 512 + k] = a * scale;
        }
    }
}

// ---------------- Legendre contraction of diff coeffs + loss; last block writes out
__global__ __launch_bounds__(256) void k_loss(const double* __restrict__ ediff,
                                              const float* __restrict__ plm,
                                              double* __restrict__ acc,
                                              int* __restrict__ counter,
                                              float* __restrict__ out) {
    int tid = threadIdx.x;
    int gtid = blockIdx.x * 256 + tid;
    int triple = gtid >> 4, j = gtid & 15;         // 16 lanes per (b,l,m)
    double c = 0.0;
    int valid = (triple < NPAIR);
    if (valid) {
        int b = triple / (LMAX * MMAX);
        int rem = triple % (LMAX * MMAX);
        int l = rem / MMAX, m = rem % MMAX;
        const double* E = ediff + ((size_t)b * MMAX + m) * 512;
        const float*  P = plm + ((size_t)l * MMAX + m) * 512;
        for (int i = 0; i < 32; ++i) {
            int k = j + (i << 4);
            c = fma((double)P[k], E[k], c);
        }
    }
    c += __shfl_xor(c, 1);
    c += __shfl_xor(c, 2);
    c += __shfl_xor(c, 4);
    c += __shfl_xor(c, 8);
    __shared__ double red[16];
    if (j == 0) red[tid >> 4] = valid ? c * c : 0.0;
    __syncthreads();
    if (tid == 0) {
        double s = 0.0;
        for (int i = 0; i < 16; ++i) s += red[i];
        atomicAdd(acc, s);                      // device-scope, coherent across XCDs
        __threadfence();
        int old = atomicAdd(counter, 1);
        if (old == (int)gridDim.x - 1) {
            double tot = atomicAdd(acc, 0.0);   // coherent read of final sum
            out[0] = (float)(tot / (double)NPAIR);
        }
    }
}

extern "C" void kernel_launch(void* const* d_in, const int* in_sizes, int n_in,
                              void* d_out, int out_size, void* d_ws, size_t ws_size,
                              hipStream_t stream) {
    const float* pred = (const float*)d_in[0];
    const float* targ = (const float*)d_in[1];

    char* ws = (char*)d_ws;
    size_t off = 0;
    auto alloc = [&](size_t bytes) -> void* {
        void* p = ws + off;
        off = (off + bytes + 255) & ~(size_t)255;
        return p;
    };
    float*  wq      = (float*) alloc(512 * sizeof(float));
    double* costab  = (double*)alloc(1024 * sizeof(double));
    float*  plm     = (float*) alloc((size_t)LMAX * MMAX * 512 * sizeof(float));
    float4* spts    = (float4*)alloc((size_t)NIMG * NPTS * sizeof(float4));
    unsigned short* bstart = (unsigned short*)alloc((size_t)NIMG * (NBINS + 1) * sizeof(unsigned short));
    float*  interp  = (float*) alloc((size_t)NIMG * M_GRID * sizeof(float));
    double* ediff   = (double*)alloc((size_t)2 * MMAX * 512 * sizeof(double));
    double* acc     = (double*)alloc(sizeof(double));
    int*    counter = (int*)   alloc(sizeof(int));
    (void)ws_size; (void)in_sizes; (void)n_in; (void)out_size;

    k_setup_bin<<<132, 256, 0, stream>>>(pred, targ, wq, costab, plm, spts, bstart,
                                         acc, counter);
    k_nn<<<NIMG * 512, 512, 0, stream>>>(spts, bstart, interp);
    k_dft<<<2 * 512, 512, 0, stream>>>(interp, costab, wq, ediff);
    int nb = (NPAIR * 16 + 255) / 256;   // 313
    k_loss<<<nb, 256, 0, stream>>>(ediff, plm, acc, counter, (float*)d_out);
}

// Round 11
// 119.567 us; speedup vs baseline: 1.0244x; 1.0244x over previous
//
#include <hip/hip_runtime.h>
#include <math.h>

#define NLAT 512
#define NLON 1024
#define LMAX 50
#define MMAX 50
#define NPTS 2048
#define NIMG 4                     // (branch<<1)|b : pred b0, pred b1, targ b0, targ b1
#define M_GRID (NLAT * NLON)       // 524288

#define NBT 32                     // theta bins over [0, pi]
#define NBP 64                     // phi bins over [-pi, pi]
#define NBINS (NBT * NBP)          // 2048
#define NPAIR (2 * LMAX * MMAX)    // 5000 (b,l,m) loss terms

// exact fp32 images of numpy float32 constants
#define PI_F     3.14159274101257324e0f   // (float)pi  0x40490FDB
#define TWO_PI_F 6.28318548202514648e0f   // (float)2pi 0x40C90FDB
#define WB       (PI_F / 32.0f)           // bin width (same in both axes)
#define INV_WB   (32.0f / PI_F)

// ---------------- merged setup (blocks 0..127) + per-image binning (blocks 128..131)
__global__ __launch_bounds__(256) void k_setup_bin(const float* __restrict__ pred,
                                                   const float* __restrict__ targ,
                                                   float* __restrict__ wq,
                                                   double* __restrict__ costab,
                                                   float* __restrict__ plm,
                                                   float4* __restrict__ spts_g,
                                                   unsigned short* __restrict__ bstart_g,
                                                   double* __restrict__ acc,
                                                   int* __restrict__ counter) {
    if (blockIdx.x < 128) {
        int tid = blockIdx.x * 256 + threadIdx.x;   // 0..32767
        if (tid == 0) { acc[0] = 0.0; counter[0] = 0; }

        // --- CC weights: one wave (64 lanes) per weight j
        {
            int j = blockIdx.x * 4 + (threadIdx.x >> 6);   // 0..511
            int lane = threadIdx.x & 63;
            double t = M_PI * (double)j / 511.0;
            double S = 0.0;
            for (int k = lane + 1; k <= 255; k += 64) {
                S += cos(2.0 * t * (double)k) * (2.0 / (4.0 * (double)k * k - 1.0));
            }
            for (int off = 32; off > 0; off >>= 1) S += __shfl_down(S, off);
            if (lane == 0) {
                double c = (j == 0 || j == 511) ? 1.0 : 2.0;
                wq[j] = (float)((c / 511.0) * (1.0 - S));
            }
        }
        if (tid < 1024) {
            costab[tid] = cos(2.0 * M_PI * (double)tid / 1024.0);
        }
        if (tid < MMAX * 512) {
            int m = tid >> 9;
            int k = tid & 511;
            double theta = M_PI * (double)k / 511.0;
            double ct = cos(theta), st = sin(theta);
            double pmm = sqrt(1.0 / (4.0 * M_PI));
            for (int i = 1; i <= m; ++i) {
                pmm = -sqrt((2.0 * i + 1.0) / (2.0 * i)) * st * pmm;
            }
            plm[((size_t)m * MMAX + m) * 512 + k] = (float)pmm;
            if (m + 1 < LMAX) {
                double pm1 = sqrt(2.0 * m + 3.0) * ct * pmm;
                plm[((size_t)(m + 1) * MMAX + m) * 512 + k] = (float)pm1;
                double pm2 = pmm;
                for (int l = m + 2; l < LMAX; ++l) {
                    double ll = (double)l, mm = (double)m, lm1 = (double)(l - 1);
                    double a  = sqrt((4.0 * ll * ll - 1.0) / (ll * ll - mm * mm));
                    double bb = sqrt((lm1 * lm1 - mm * mm) / (4.0 * lm1 * lm1 - 1.0));
                    double p = a * (ct * pm1 - bb * pm2);
                    plm[((size_t)l * MMAX + m) * 512 + k] = (float)p;
                    pm2 = pm1; pm1 = p;
                }
            }
        }
        return;
    }

    // ---- binning path: one block per image
    int img = blockIdx.x - 128;
    int branch = img >> 1, b = img & 1;
    const float* src = (branch ? targ : pred) + (size_t)b * NPTS * 3;
    __shared__ float sth[NPTS], sphi[NPTS], srr[NPTS];   // 24 KB
    __shared__ int cnt[NBINS];                            // 8 KB
    __shared__ int bstart[NBINS];                         // 8 KB
    __shared__ int partial[256];
    __shared__ int binid[NPTS];                           // 8 KB
    int tid = threadIdx.x;

    for (int i = tid; i < NBINS; i += 256) cnt[i] = 0;
    for (int i = tid; i < NPTS; i += 256) {
        float x = src[3 * i], y = src[3 * i + 1], z = src[3 * i + 2];
        float r = sqrtf(x * x + y * y + z * z);
        float nyz = sqrtf(y * y + z * z);
        float phi1 = acosf(x / r);
        float base = acosf(y / nyz);
        float phi2 = (z < 0.0f) ? (TWO_PI_F - base) : base;
        sth[i] = phi1; sphi[i] = phi2 - PI_F; srr[i] = r;
    }
    __syncthreads();
    for (int i = tid; i < NPTS; i += 256) {
        int bt = min(max((int)(sth[i] * INV_WB), 0), NBT - 1);
        int bp = min(max((int)((sphi[i] + PI_F) * INV_WB), 0), NBP - 1);
        int bn = bt * NBP + bp;
        binid[i] = bn;
        atomicAdd(&cnt[bn], 1);
    }
    __syncthreads();
    // exclusive scan over 2048 bins: 8 bins per thread + scan of 256 partials
    int base = tid * 8, s = 0;
    #pragma unroll
    for (int j = 0; j < 8; ++j) s += cnt[base + j];
    partial[tid] = s;
    __syncthreads();
    for (int offs = 1; offs < 256; offs <<= 1) {
        int v = (tid >= offs) ? partial[tid - offs] : 0;
        __syncthreads();
        partial[tid] += v;
        __syncthreads();
    }
    int run = (tid == 0) ? 0 : partial[tid - 1];
    #pragma unroll
    for (int j = 0; j < 8; ++j) { bstart[base + j] = run; run += cnt[base + j]; }
    __syncthreads();
    unsigned short* bsg = bstart_g + (size_t)img * (NBINS + 1);
    for (int i = tid; i < NBINS; i += 256) {
        bsg[i] = (unsigned short)bstart[i];
        cnt[i] = bstart[i];
    }
    if (tid == 0) bsg[NBINS] = (unsigned short)NPTS;
    __syncthreads();
    float4* sg = spts_g + (size_t)img * NPTS;
    for (int i = tid; i < NPTS; i += 256) {
        int bn = binid[i];
        int pos = atomicAdd(&cnt[bn], 1);   // within-bin order nondeterministic; value-safe
        sg[pos] = make_float4(sth[i], sphi[i], srr[i], 0.0f);
    }
}

// ---------------- binned 3-NN + interp: one WAVE per 8x16 patch (2 queries/lane),
// row-span ring scan, 512-thread blocks (4 blocks/CU -> full occupancy)
// [R10 span-prefetch variant reverted: at 32 waves/CU, TLP already hides the
//  dependent sstart reads; the extra bookkeeping cost ~3 us — measured]
__global__ __launch_bounds__(512, 8) void k_nn(const float4* __restrict__ spts_g,
                                               const unsigned short* __restrict__ bstart_g,
                                               float* __restrict__ interp) {
    __shared__ float4 spts[NPTS];                  // 32 KB
    __shared__ unsigned short sstart[NBINS + 1];   // 4 KB
    int bid = blockIdx.x;
    int img = bid >> 9;                            // 512 blocks per image
    int blk = bid & 511;
    const float4* sg = spts_g + (size_t)img * NPTS;
    const unsigned short* bsg = bstart_g + (size_t)img * (NBINS + 1);
    int tid = threadIdx.x;
    for (int i = tid; i < NPTS; i += 512) spts[i] = sg[i];
    for (int i = tid; i < NBINS + 1; i += 512) sstart[i] = bsg[i];
    __syncthreads();

    // 8 waves/block; wave w -> patch blk*8+w of a 64x64 grid of 8(theta)x16(phi) patches
    int w = tid >> 6, lane = tid & 63;
    int patch = blk * 8 + w;
    int pi = patch >> 6, pj = patch & 63;
    int qi = lane >> 3, qj0 = (lane & 7) * 2;      // two phi-adjacent queries per lane
    int gi = pi * 8 + qi;
    int gj0 = pj * 16 + qj0, gj1 = gj0 + 1;
    float gt  = (float)gi * (1.0f / 512.0f) * PI_F;
    float gp0 = (float)(gj0 - 512) * (1.0f / 512.0f) * PI_F;   // independent rounding:
    float gp1 = (float)(gj1 - 512) * (1.0f / 512.0f) * PI_F;   // exact fp32 ref match
    int qbt  = min(max((int)(gt * INV_WB), 0), NBT - 1);
    int qbp0 = min(max((int)((gp0 + PI_F) * INV_WB), 0), NBP - 1);
    int qbp1 = min(max((int)((gp1 + PI_F) * INV_WB), 0), NBP - 1);
    // binning monotone in gi/gj -> lane 0 query0 is bbox min, lane 63 query1 is bbox max
    int bt0 = __shfl(qbt, 0), bt1 = __shfl(qbt, 63);
    int bp0 = __shfl(qbp0, 0), bp1 = __shfl(qbp1, 63);

    float da0 = 1e30f, da1 = 1e30f, da2 = 1e30f;   // top-3 for query A (gp0)
    float ra0 = 0.0f, ra1 = 0.0f, ra2 = 0.0f;
    float db0 = 1e30f, db1 = 1e30f, db2 = 1e30f;   // top-3 for query B (gp1)
    float rb0 = 0.0f, rb1 = 0.0f, rb2 = 0.0f;

    // contiguous point-span over bins (t, p0..p1): counting-sort layout is bin-major,
    // so one row of bins = one span. Point sequence identical to per-bin scanning.
    auto scan_span = [&](int t, int p0, int p1) {
        int s = sstart[t * NBP + p0], e = sstart[t * NBP + p1 + 1];
        for (int i = s; i < e; ++i) {
            float4 pt = spts[i];                   // wave-uniform LDS read: broadcast
            float dx  = gt - pt.x;
            float dxx = dx * dx;
            float dy0 = gp0 - pt.y;
            float dy1 = gp1 - pt.y;
            float dA  = fmaf(dy0, dy0, dxx);
            float dB  = fmaf(dy1, dy1, dxx);
            if (__any(dA < da2 || dB < db2)) {     // wave-uniform skip of the inserts
                float rv = pt.z;
                bool c2 = dA < da2, c1 = dA < da1, c0 = dA < da0;
                da2 = c1 ? da1 : (c2 ? dA : da2);   ra2 = c1 ? ra1 : (c2 ? rv : ra2);
                da1 = c0 ? da0 : (c1 ? dA : da1);   ra1 = c0 ? ra0 : (c1 ? rv : ra1);
                da0 = c0 ? dA : da0;                ra0 = c0 ? rv : ra0;
                bool e2 = dB < db2, e1 = dB < db1, e0 = dB < db0;
                db2 = e1 ? db1 : (e2 ? dB : db2);   rb2 = e1 ? rb1 : (e2 ? rv : rb2);
                db1 = e0 ? db0 : (e1 ? dB : db1);   rb1 = e0 ? rb0 : (e1 ? rv : rb1);
                db0 = e0 ? dB : db0;                rb0 = e0 ? rv : rb0;
            }
        }
    };

    // r = 0: bbox rows
    for (int t = bt0; t <= bt1; ++t) scan_span(t, bp0, bp1);
    for (int r = 1; r <= 70; ++r) {
        if (r >= 2) {
            // rings 0..r-1 complete: unscanned points are >= (r-1)*WB away
            // (d2 = 1e30 until 3 inserts -> bound test fails automatically)
            float bnd = (float)(r - 1) * WB * 0.999f;
            float b2 = bnd * bnd;
            if (__all(b2 > da2 && b2 > db2)) break;   // wave-level vote, no barrier
        }
        int tlo = bt0 - r, thi = bt1 + r, plo = bp0 - r, phi = bp1 + r;
        int cplo = max(plo, 0), cphi = min(phi, NBP - 1);
        if (tlo >= 0)       scan_span(tlo, cplo, cphi);
        if (thi <= NBT - 1) scan_span(thi, cplo, cphi);
        int ctlo = max(tlo + 1, 0), cthi = min(thi - 1, NBT - 1);
        if (plo >= 0)       for (int t = ctlo; t <= cthi; ++t) scan_span(t, plo, plo);
        if (phi <= NBP - 1) for (int t = ctlo; t <= cthi; ++t) scan_span(t, phi, phi);
        if (tlo <= 0 && thi >= NBT - 1 && plo <= 0 && phi >= NBP - 1) break;
    }
    float sA = da0 + da1 + da2;     // faithful: weights proportional to distance
    float sB = db0 + db1 + db2;
    float2 outv;
    outv.x = (da0 * ra0 + da1 * ra1 + da2 * ra2) / sA;
    outv.y = (db0 * rb0 + db1 * rb1 + db2 * rb2) / sB;
    *(float2*)&interp[(size_t)img * M_GRID + (size_t)gi * NLON + gj0] = outv;
}

// ---------------- DFT of the DIFFERENCE field (SHT is linear): E[b,m,k] =
// wq[k]*(2pi/N)*Re rfft(interp[pred,b]-interp[targ,b])[k,m].  1024 rows, 8 waves/blk.
__global__ __launch_bounds__(512) void k_dft(const float* __restrict__ interp,
                                             const double* __restrict__ costab,
                                             const float* __restrict__ wq,
                                             double* __restrict__ ediff) {
    __shared__ double sdf[NLON];     // 8 KB: fp64 diff of the two fp32 rows
    __shared__ double sct[NLON];     // 8 KB
    __shared__ double g[576];        // 4.5 KB (g[513..575] = 0 pad)
    int bid = blockIdx.x;            // one block per (batch, k) row: 1024 rows
    int b = bid >> 9, k = bid & 511;
    const float* rowp = interp + (size_t)b * M_GRID + (size_t)k * NLON;        // pred
    const float* rowt = interp + (size_t)(2 + b) * M_GRID + (size_t)k * NLON;  // targ
    int tid = threadIdx.x;
    for (int i = tid; i < NLON; i += 512) {
        sdf[i] = (double)rowp[i] - (double)rowt[i];   // exact in fp64
        sct[i] = costab[i];
    }
    __syncthreads();
    // fold: g[n] = d[n] + d[1024-n] (n=1..511), g[0]=d[0], g[512]=d[512]
    for (int n = tid; n < 576; n += 512) {
        double v = 0.0;
        if (n == 0) v = sdf[0];
        else if (n < 512) v = sdf[n] + sdf[1024 - n];
        else if (n == 512) v = sdf[512];
        g[n] = v;
    }
    __syncthreads();
    double scale = (double)wq[k] * (6.283185307179586 / 1024.0);
    int w = tid >> 6, lane = tid & 63;
    for (int m = w; m < MMAX; m += 8) {
        // cos/sin at theta = 2*pi*m*lane/1024; sin(x) = cos(x - pi/2) -> idx +768
        double c  = sct[(m * lane) & 1023];
        double s  = sct[(m * lane + 768) & 1023];
        double cd = sct[(m * 64) & 1023];          // rotation by delta = 2*pi*m*64/1024
        double sd = sct[(m * 64 + 768) & 1023];
        double a = 0.0;
        #pragma unroll
        for (int i = 0; i < 9; ++i) {
            int n = lane + (i << 6);               // lane-consecutive: conflict-free
            a = fma(g[n], c, a);
            double cn = fma(cd, c, -(sd * s));
            double sn = fma(cd, s, sd * c);
            c = cn; s = sn;
        }
        #pragma unroll
        for (int off = 32; off > 0; off >>= 1) a += __shfl_xor(a, off);
        if (lane == 0) {
            ediff[((size_t)b * MMAX + m) * 512 + k] = a * scale;
        }
    }
}

// ---------------- Legendre contraction of diff coeffs + loss; last block writes out
__global__ __launch_bounds__(256) void k_loss(const double* __restrict__ ediff,
                                              const float* __restrict__ plm,
                                              double* __restrict__ acc,
                                              int* __restrict__ counter,
                                              float* __restrict__ out) {
    int tid = threadIdx.x;
    int gtid = blockIdx.x * 256 + tid;
    int triple = gtid >> 4, j = gtid & 15;         // 16 lanes per (b,l,m)
    double c = 0.0;
    int valid = (triple < NPAIR);
    if (valid) {
        int b = triple / (LMAX * MMAX);
        int rem = triple % (LMAX * MMAX);
        int l = rem / MMAX, m = rem % MMAX;
        const double* E = ediff + ((size_t)b * MMAX + m) * 512;
        const float*  P = plm + ((size_t)l * MMAX + m) * 512;
        for (int i = 0; i < 32; ++i) {
            int k = j + (i << 4);
            c = fma((double)P[k], E[k], c);
        }
    }
    c += __shfl_xor(c, 1);
    c += __shfl_xor(c, 2);
    c += __shfl_xor(c, 4);
    c += __shfl_xor(c, 8);
    __shared__ double red[16];
    if (j == 0) red[tid >> 4] = valid ? c * c : 0.0;
    __syncthreads();
    if (tid == 0) {
        double s = 0.0;
        for (int i = 0; i < 16; ++i) s += red[i];
        atomicAdd(acc, s);                      // device-scope, coherent across XCDs
        __threadfence();
        int old = atomicAdd(counter, 1);
        if (old == (int)gridDim.x - 1) {
            double tot = atomicAdd(acc, 0.0);   // coherent read of final sum
            out[0] = (float)(tot / (double)NPAIR);
        }
    }
}

extern "C" void kernel_launch(void* const* d_in, const int* in_sizes, int n_in,
                              void* d_out, int out_size, void* d_ws, size_t ws_size,
                              hipStream_t stream) {
    const float* pred = (const float*)d_in[0];
    const float* targ = (const float*)d_in[1];

    char* ws = (char*)d_ws;
    size_t off = 0;
    auto alloc = [&](size_t bytes) -> void* {
        void* p = ws + off;
        off = (off + bytes + 255) & ~(size_t)255;
        return p;
    };
    float*  wq      = (float*) alloc(512 * sizeof(float));
    double* costab  = (double*)alloc(1024 * sizeof(double));
    float*  plm     = (float*) alloc((size_t)LMAX * MMAX * 512 * sizeof(float));
    float4* spts    = (float4*)alloc((size_t)NIMG * NPTS * sizeof(float4));
    unsigned short* bstart = (unsigned short*)alloc((size_t)NIMG * (NBINS + 1) * sizeof(unsigned short));
    float*  interp  = (float*) alloc((size_t)NIMG * M_GRID * sizeof(float));
    double* ediff   = (double*)alloc((size_t)2 * MMAX * 512 * sizeof(double));
    double* acc     = (double*)alloc(sizeof(double));
    int*    counter = (int*)   alloc(sizeof(int));
    (void)ws_size; (void)in_sizes; (void)n_in; (void)out_size;

    k_setup_bin<<<132, 256, 0, stream>>>(pred, targ, wq, costab, plm, spts, bstart,
                                         acc, counter);
    k_nn<<<NIMG * 512, 512, 0, stream>>>(spts, bstart, interp);
    k_dft<<<2 * 512, 512, 0, stream>>>(interp, costab, wq, ediff);
    int nb = (NPAIR * 16 + 255) / 256;   // 313
    k_loss<<<nb, 256, 0, stream>>>(ediff, plm, acc, counter, (float*)d_out);
}